// Round 8
// baseline (212.606 us; speedup 1.0000x reference)
//
#include <hip/hip_runtime.h>

// ---------------------------------------------------------------------------
// CausalSelfAttention forward on MI355X (gfx950).
// B=4, T=2048, C=1024, H=16, hs=64.
// Pipeline: [cvt x->bf16, transpose W's] -> QKV GEMM (128x256 2-phase/K-tile
//           pipelined bf16 MFMA) -> flash attention (swapped-QK, pair-merged
//           kv sweep) -> proj GEMM (same template).
// Workspace layout (bytes):
//   xb    @ 0         : 8192x1024 bf16           (16,777,216)
//   WaT   @ 16777216  : 3072x1024 bf16           ( 6,291,456)
//   WpT   @ 23068672  : 1024x1024 bf16           ( 2,097,152)
//   Q     @ 25165824  : [64][2048][64] bf16      (pre-scaled by log2e/8)
//   K     @ 41943040  : [64][2048][64] bf16
//   Vt    @ 58720256  : [64][64][2048] bf16      (V transposed per head)
//   Y     @ 75497472  : 8192x1024 bf16
// ---------------------------------------------------------------------------

typedef __bf16 bf16_t;
typedef __bf16 bf16x8 __attribute__((ext_vector_type(8)));
typedef __bf16 bf16x4 __attribute__((ext_vector_type(4)));
typedef float  f32x4  __attribute__((ext_vector_type(4)));

#define MFMA16(a, b, c) __builtin_amdgcn_mfma_f32_16x16x32_bf16((a), (b), (c), 0, 0, 0)

static __device__ __forceinline__ void gld_lds16(const bf16_t* g, void* l) {
  __builtin_amdgcn_global_load_lds(
      (const __attribute__((address_space(1))) void*)(const void*)g,
      (__attribute__((address_space(3))) void*)l, 16, 0, 0);
}

static __device__ __forceinline__ bf16x8 ldv8(const void* p) {
  return *reinterpret_cast<const bf16x8*>(p);
}

static __device__ __forceinline__ float exp2_hw(float x) {
  float r;
  asm("v_exp_f32 %0, %1" : "=v"(r) : "v"(x));
  return r;
}

// ---------------------------------------------------------------- prep ----
__global__ __launch_bounds__(256) void cvt_f32_bf16(const float* __restrict__ in,
                                                    bf16_t* __restrict__ out, int n4) {
  int i = blockIdx.x * 256 + threadIdx.x;
  if (i < n4) {
    float4 v = reinterpret_cast<const float4*>(in)[i];
    bf16x4 o;
    o[0] = (bf16_t)v.x; o[1] = (bf16_t)v.y; o[2] = (bf16_t)v.z; o[3] = (bf16_t)v.w;
    reinterpret_cast<bf16x4*>(out)[i] = o;
  }
}

// in [Kd][Nd] f32  ->  out [Nd][Kd] bf16
__global__ __launch_bounds__(256) void transpose_cvt(const float* __restrict__ in,
                                                     bf16_t* __restrict__ out,
                                                     int Kd, int Nd) {
  __shared__ float tile[32][33];
  int tx = threadIdx.x, ty = threadIdx.y;
  int n0 = blockIdx.x * 32, k0 = blockIdx.y * 32;
#pragma unroll
  for (int i = 0; i < 4; ++i)
    tile[ty + i * 8][tx] = in[(size_t)(k0 + ty + i * 8) * Nd + (n0 + tx)];
  __syncthreads();
#pragma unroll
  for (int i = 0; i < 4; ++i)
    out[(size_t)(n0 + ty + i * 8) * Kd + (k0 + tx)] = (bf16_t)tile[tx][ty + i * 8];
}

// ---------------------------------------------------------------- GEMM ----
// 128(M) x 256(N) tile, BK=64, 8 waves (2m x 4n, wave tile 64x64), 512 thr.
// LDS 96KB: A dbuf 2x16KB @0, B dbuf 2x32KB @32768. Double-buffered, TWO
// phases per K-tile, each: {ds_read frag subtile; (phase A only: issue all 6
// gld_lds for kt+1) ; barrier ; lgkmcnt(0) ; setprio(1) ; 16 MFMA ;
// setprio(0) ; [phase B: vmcnt(0)] ; barrier}. Source-side XOR swizzle (G21)
// -> conflict-free ds_read_b128. XCD-bijective block swizzle (nwg%8==0).
// MODE 0: scatter qkv -> Q (x log2e/8), K, Vt. MODE 1: f32 out.
template <int MODE>
__global__ __launch_bounds__(512) void gemm_bf16(
    const bf16_t* __restrict__ A, const bf16_t* __restrict__ Bt,
    const float* __restrict__ bias, int M, int N, int K,
    bf16_t* __restrict__ Qo, bf16_t* __restrict__ Ko, bf16_t* __restrict__ Vt,
    float* __restrict__ Co) {
  __shared__ alignas(16) char lds[98304];  // A 2x16K @0, B 2x32K @32768

  const int tid = threadIdx.x;
  const int wave = tid >> 6, lane = tid & 63;
  const int wm = wave >> 2, wn = wave & 3;   // 2 x 4 wave grid
  const int l16 = lane & 15, kb = lane >> 4;

  // XCD-bijective swizzle of the linearized block id (nwg % 8 == 0)
  const int nbx = gridDim.x;
  const int lb = blockIdx.y * nbx + blockIdx.x;
  const int cpx = (nbx * gridDim.y) >> 3;
  const int sw = (lb & 7) * cpx + (lb >> 3);
  const int tm0 = (sw / nbx) * 128, tn0 = (sw % nbx) * 256;

  // staging: thread -> (row = tid>>3 within 64-row group, 16B chunk tid&7),
  // source chunk pre-swizzled so linear LDS dest == swizzled layout (G21).
  const int srow = tid >> 3;                 // 0..63
  const int sch = (tid & 7) ^ (srow & 7);    // row&7 == srow&7 (64 | inst*64)
  const bf16_t* aSrc = A + (size_t)(tm0 + srow) * K + sch * 8;
  const bf16_t* bSrc = Bt + (size_t)(tn0 + srow) * K + sch * 8;

  auto stage = [&](int buf, int k0) {
    char* ad = lds + buf * 16384 + wave * 1024;
    char* bd = lds + 32768 + buf * 32768 + wave * 1024;
#pragma unroll
    for (int inst = 0; inst < 2; ++inst)     // A: 128 rows
      gld_lds16(aSrc + (size_t)(inst * 64) * K + k0, ad + inst * 8192);
#pragma unroll
    for (int inst = 0; inst < 4; ++inst)     // B: 256 rows
      gld_lds16(bSrc + (size_t)(inst * 64) * K + k0, bd + inst * 8192);
  };

  f32x4 acc[4][4] = {};
  const int NK = K >> 6;

  stage(0, 0);
  asm volatile("s_waitcnt vmcnt(0)" ::: "memory");
  __builtin_amdgcn_s_barrier();
  __builtin_amdgcn_sched_barrier(0);

  for (int kt = 0; kt < NK; ++kt) {
    const int buf = kt & 1;
    const bool more = (kt + 1 < NK);
    const char* Ab = lds + buf * 16384;
    const char* Bb = lds + 32768 + buf * 32768;
    const int arow = wm * 64 + l16;          // +mi*16
    const int brow = wn * 64 + l16;          // +ni*16
    const int r7 = l16 & 7;

    // ---- phase A: all A frags + B frags (ni 0,1); issue kt+1 staging ----
    bf16x8 af[4][2], bf01[2][2];
#pragma unroll
    for (int mi = 0; mi < 4; ++mi)
#pragma unroll
      for (int kc = 0; kc < 2; ++kc)
        af[mi][kc] = ldv8(Ab + (arow + mi * 16) * 128 + (((kc * 4 + kb) ^ r7) * 16));
#pragma unroll
    for (int ni = 0; ni < 2; ++ni)
#pragma unroll
      for (int kc = 0; kc < 2; ++kc)
        bf01[ni][kc] = ldv8(Bb + (brow + ni * 16) * 128 + (((kc * 4 + kb) ^ r7) * 16));
    if (more) stage(buf ^ 1, (kt + 1) * 64);
    __builtin_amdgcn_s_barrier();
    asm volatile("s_waitcnt lgkmcnt(0)" ::: "memory");
    __builtin_amdgcn_sched_barrier(0);
    __builtin_amdgcn_s_setprio(1);
#pragma unroll
    for (int mi = 0; mi < 4; ++mi)
#pragma unroll
      for (int ni = 0; ni < 2; ++ni)
#pragma unroll
        for (int kc = 0; kc < 2; ++kc)
          acc[mi][ni] = MFMA16(af[mi][kc], bf01[ni][kc], acc[mi][ni]);
    __builtin_amdgcn_s_setprio(0);
    __builtin_amdgcn_s_barrier();

    // ---- phase B: B frags (ni 2,3); counted drain once per K-tile ----
    bf16x8 bf23[2][2];
#pragma unroll
    for (int ni = 0; ni < 2; ++ni)
#pragma unroll
      for (int kc = 0; kc < 2; ++kc)
        bf23[ni][kc] = ldv8(Bb + (brow + (2 + ni) * 16) * 128 + (((kc * 4 + kb) ^ r7) * 16));
    __builtin_amdgcn_s_barrier();
    asm volatile("s_waitcnt lgkmcnt(0)" ::: "memory");
    __builtin_amdgcn_sched_barrier(0);
    __builtin_amdgcn_s_setprio(1);
#pragma unroll
    for (int mi = 0; mi < 4; ++mi)
#pragma unroll
      for (int ni = 0; ni < 2; ++ni)
#pragma unroll
        for (int kc = 0; kc < 2; ++kc)
          acc[mi][2 + ni] = MFMA16(af[mi][kc], bf23[ni][kc], acc[mi][2 + ni]);
    __builtin_amdgcn_s_setprio(0);
    asm volatile("s_waitcnt vmcnt(0)" ::: "memory");  // kt+1 tiles landed
    __builtin_amdgcn_s_barrier();
    __builtin_amdgcn_sched_barrier(0);
  }

  // epilogue: C/D layout col=lane&15, row=(lane>>4)*4+j  [verified m89]
#pragma unroll
  for (int ni = 0; ni < 4; ++ni) {
    const int n = tn0 + wn * 64 + ni * 16 + l16;
    const float bv = bias[n];
#pragma unroll
    for (int mi = 0; mi < 4; ++mi) {
#pragma unroll
      for (int j = 0; j < 4; ++j) {
        const int m = tm0 + wm * 64 + mi * 16 + kb * 4 + j;
        const float v = acc[mi][ni][j] + bv;
        if constexpr (MODE == 0) {
          const int which = n >> 10, hn = n & 1023;
          const int h = hn >> 6, d = hn & 63;
          const int b = m >> 11, t = m & 2047;
          const size_t bh = (size_t)(b * 16 + h);
          if (which == 0)  // fold 1/sqrt(hs) * log2(e) for base-2 softmax
            Qo[(bh * 2048 + t) * 64 + d] = (bf16_t)(v * 0.18033688011112042f);
          else if (which == 1)
            Ko[(bh * 2048 + t) * 64 + d] = (bf16_t)v;
          else
            Vt[(bh * 64 + d) * 2048 + t] = (bf16_t)v;
        } else {
          Co[(size_t)m * N + n] = v;
        }
      }
    }
  }
}

// ----------------------------------------------------------- attention ----
// (unchanged from round 7 — 85 µs, verified)
// Pair-merged sweep (q-tiles A=pp, B=31-pp, one kv sweep 0..31-pp; A active
// while t <= pp). Swapped-QK: lane owns one q-row per tile-state.
// LDS 40KB (K 2x8K, V 2x8K, P 8K shared). Defer-max base-2 softmax,
// per-kb-lane partial l_r reduced in epilogue.
__global__ __launch_bounds__(256) void attn_fwd(const bf16_t* __restrict__ Qg,
                                                const bf16_t* __restrict__ Kg,
                                                const bf16_t* __restrict__ Vtg,
                                                bf16_t* __restrict__ Yg) {
  __shared__ alignas(16) char lds[40960];  // K 2x8K @0, V 2x8K @16384, P 8K @32768

  const int tid = threadIdx.x;
  const int wave = tid >> 6, lane = tid & 63;
  const int l16 = lane & 15, kb = lane >> 4;
  const int l8 = l16 & 7;
  const float NEG_INF = -__builtin_inff();

  const int n = blockIdx.x;                    // 1024 blocks
  const int bh = (n & 7) * 8 + ((n >> 3) & 7); // 8 heads per XCD
  const int pp = n >> 6;                       // pair index [0,16)
  const size_t base = (size_t)bh * (2048 * 64);
  const int b = bh >> 4, h = bh & 15;

  const int srow = tid >> 3;
  const int schunk = (tid & 7) ^ (srow & 7);
  const bf16_t* Ksrc = Kg + base + (size_t)srow * 64 + schunk * 8;
  const bf16_t* Vsrc = Vtg + base + (size_t)srow * 2048 + schunk * 8;

  auto stageK = [&](int buf, int kv0) {
    char* kd = lds + buf * 8192 + wave * 1024;
    const bf16_t* ks = Ksrc + (size_t)kv0 * 64;
    gld_lds16(ks, kd);
    gld_lds16(ks + 2048, kd + 4096);
  };
  auto stageV = [&](int buf, int kv0) {
    char* vd = lds + 16384 + buf * 8192 + wave * 1024;
    const bf16_t* vs = Vsrc + kv0;
    gld_lds16(vs, vd);
    gld_lds16(vs + 65536, vd + 4096);
  };

  const int qtA = pp, qtB = 31 - pp;
  const int trips = 32 - pp;
  const int qA = qtA * 64 + wave * 16 + l16;
  const int qB = qtB * 64 + wave * 16 + l16;

  const bf16x8 qfA0 = ldv8(Qg + base + (size_t)qA * 64 + kb * 8);
  const bf16x8 qfA1 = ldv8(Qg + base + (size_t)qA * 64 + 32 + kb * 8);
  const bf16x8 qfB0 = ldv8(Qg + base + (size_t)qB * 64 + kb * 8);
  const bf16x8 qfB1 = ldv8(Qg + base + (size_t)qB * 64 + 32 + kb * 8);

  f32x4 oA[4] = {}, oB[4] = {};
  float mA = NEG_INF, lA = 0.f, mB = NEG_INF, lB = 0.f;

  auto online_sm = [&](f32x4 (&s)[4], bf16x4 (&pw)[4], f32x4 (&o)[4],
                       float& m_r, float& l_r, int q, int kv0, bool diag) {
    float pm[4];
#pragma unroll
    for (int i = 0; i < 4; ++i) {
      f32x4 sv = s[i];
      if (diag) {
#pragma unroll
        for (int j = 0; j < 4; ++j)
          if (kv0 + i * 16 + kb * 4 + j > q) sv[j] = NEG_INF;
        s[i] = sv;
      }
      pm[i] = fmaxf(fmaxf(sv[0], sv[1]), fmaxf(sv[2], sv[3]));
    }
    float mx = fmaxf(fmaxf(pm[0], pm[1]), fmaxf(pm[2], pm[3]));
    if (__any(mx > m_r + 8.0f)) {              // rare: full reduce + rescale
      mx = fmaxf(mx, __shfl_xor(mx, 16));
      mx = fmaxf(mx, __shfl_xor(mx, 32));
      const float mn = fmaxf(m_r, mx);
      const float sc = exp2_hw(m_r - mn);
      l_r *= sc;
#pragma unroll
      for (int i = 0; i < 4; ++i) {
        o[i][0] *= sc; o[i][1] *= sc; o[i][2] *= sc; o[i][3] *= sc;
      }
      m_r = mn;
    }
    float ss = 0.f;
#pragma unroll
    for (int i = 0; i < 4; ++i)
#pragma unroll
      for (int j = 0; j < 4; ++j) {
        const float p = exp2_hw(s[i][j] - m_r);
        ss += p;
        pw[i][j] = (bf16_t)p;
      }
    l_r += ss;                                  // partial; reduced in epilogue
  };

  auto p_roundtrip = [&](char* Pp, const bf16x4 (&pw)[4], bf16x8& pb0, bf16x8& pb1) {
#pragma unroll
    for (int i = 0; i < 4; ++i) {
      const int phys = (i * 2 + (kb >> 1)) ^ l8;
      *reinterpret_cast<bf16x4*>(Pp + l16 * 128 + phys * 16 + (kb & 1) * 8) = pw[i];
    }
    pb0 = ldv8(Pp + l16 * 128 + ((kb ^ l8) * 16));
    pb1 = ldv8(Pp + l16 * 128 + (((4 + kb) ^ l8) * 16));
  };

  char* Pw = lds + 32768 + wave * 2048;

  stageK(0, 0);
  stageV(0, 0);
  asm volatile("s_waitcnt vmcnt(0)" ::: "memory");
  __builtin_amdgcn_s_barrier();
  __builtin_amdgcn_sched_barrier(0);

  int cur = 0;
  for (int t = 0; t < trips; ++t) {
    const int kv0 = t * 64;
    const bool more = (t + 1 < trips);
    if (more) {
      stageK(cur ^ 1, kv0 + 64);
      stageV(cur ^ 1, kv0 + 64);
    }
    const bool aAct = (t <= pp);

    const char* Kb = lds + cur * 8192;
    const char* Vb = lds + 16384 + cur * 8192;

    bf16x8 kf[8];
#pragma unroll
    for (int i = 0; i < 4; ++i) {
      const int row = i * 16 + l16;
#pragma unroll
      for (int kc = 0; kc < 2; ++kc)
        kf[i * 2 + kc] = ldv8(Kb + row * 128 + (((kc * 4 + kb) ^ (row & 7)) * 16));
    }

    f32x4 sA[4] = {}, sB[4] = {};
    __builtin_amdgcn_s_setprio(1);
#pragma unroll
    for (int i = 0; i < 4; ++i) {
      sB[i] = MFMA16(kf[i * 2 + 0], qfB0, sB[i]);
      sB[i] = MFMA16(kf[i * 2 + 1], qfB1, sB[i]);
    }
    if (aAct) {
#pragma unroll
      for (int i = 0; i < 4; ++i) {
        sA[i] = MFMA16(kf[i * 2 + 0], qfA0, sA[i]);
        sA[i] = MFMA16(kf[i * 2 + 1], qfA1, sA[i]);
      }
    }
    __builtin_amdgcn_s_setprio(0);

    bf16x8 vf[8];
#pragma unroll
    for (int i = 0; i < 4; ++i) {
      const int row = i * 16 + l16;
#pragma unroll
      for (int kc = 0; kc < 2; ++kc)
        vf[i * 2 + kc] = ldv8(Vb + row * 128 + (((kc * 4 + kb) ^ (row & 7)) * 16));
    }

    bf16x4 pwA[4], pwB[4];
    bf16x8 pbA0, pbA1, pbB0, pbB1;
    online_sm(sB, pwB, oB, mB, lB, qB, kv0, t == trips - 1);
    p_roundtrip(Pw, pwB, pbB0, pbB1);
    if (aAct) {
      online_sm(sA, pwA, oA, mA, lA, qA, kv0, t == pp);
      p_roundtrip(Pw, pwA, pbA0, pbA1);
    }

    __builtin_amdgcn_s_setprio(1);
#pragma unroll
    for (int i = 0; i < 4; ++i) {
      oB[i] = MFMA16(vf[i * 2 + 0], pbB0, oB[i]);
      oB[i] = MFMA16(vf[i * 2 + 1], pbB1, oB[i]);
    }
    if (aAct) {
#pragma unroll
      for (int i = 0; i < 4; ++i) {
        oA[i] = MFMA16(vf[i * 2 + 0], pbA0, oA[i]);
        oA[i] = MFMA16(vf[i * 2 + 1], pbA1, oA[i]);
      }
    }
    __builtin_amdgcn_s_setprio(0);

    asm volatile("s_waitcnt vmcnt(0)" ::: "memory");
    __builtin_amdgcn_s_barrier();
    __builtin_amdgcn_sched_barrier(0);
    cur ^= 1;
  }

  auto epi = [&](const f32x4 (&o)[4], float l_r, int q) {
    float lt = l_r + __shfl_xor(l_r, 16);
    lt += __shfl_xor(lt, 32);
    const float inv = 1.0f / lt;
    bf16_t* yrow = Yg + ((size_t)(b * 2048 + q)) * 1024 + h * 64;
#pragma unroll
    for (int i = 0; i < 4; ++i) {
      bf16x4 yv;
      yv[0] = (bf16_t)(o[i][0] * inv);
      yv[1] = (bf16_t)(o[i][1] * inv);
      yv[2] = (bf16_t)(o[i][2] * inv);
      yv[3] = (bf16_t)(o[i][3] * inv);
      *reinterpret_cast<bf16x4*>(yrow + i * 16 + kb * 4) = yv;
    }
  };
  epi(oB, lB, qB);
  epi(oA, lA, qA);
}

// --------------------------------------------------------------- launch ---
extern "C" void kernel_launch(void* const* d_in, const int* in_sizes, int n_in,
                              void* d_out, int out_size, void* d_ws, size_t ws_size,
                              hipStream_t stream) {
  const float* x = (const float*)d_in[0];
  const float* W_attn = (const float*)d_in[1];
  const float* b_attn = (const float*)d_in[2];
  const float* W_proj = (const float*)d_in[3];
  const float* b_proj = (const float*)d_in[4];
  float* out = (float*)d_out;

  char* ws = (char*)d_ws;
  bf16_t* xb  = (bf16_t*)(ws + 0);
  bf16_t* WaT = (bf16_t*)(ws + 16777216);
  bf16_t* WpT = (bf16_t*)(ws + 23068672);
  bf16_t* Qb  = (bf16_t*)(ws + 25165824);
  bf16_t* Kb  = (bf16_t*)(ws + 41943040);
  bf16_t* Vt  = (bf16_t*)(ws + 58720256);
  bf16_t* Yb  = (bf16_t*)(ws + 75497472);

  cvt_f32_bf16<<<8192, 256, 0, stream>>>(x, xb, 8192 * 1024 / 4);
  transpose_cvt<<<dim3(96, 32), dim3(32, 8), 0, stream>>>(W_attn, WaT, 1024, 3072);
  transpose_cvt<<<dim3(32, 32), dim3(32, 8), 0, stream>>>(W_proj, WpT, 1024, 1024);

  // qkv: M=8192, N=3072 -> grid 12x64 = 768 blocks (3 exact CU rounds)
  gemm_bf16<0><<<dim3(12, 64), 512, 0, stream>>>(xb, WaT, b_attn, 8192, 3072, 1024,
                                                 Qb, Kb, Vt, nullptr);

  attn_fwd<<<1024, 256, 0, stream>>>(Qb, Kb, Vt, Yb);

  // proj: M=8192, N=1024 -> grid 4x64 = 256 blocks (1 exact CU round)
  gemm_bf16<1><<<dim3(4, 64), 512, 0, stream>>>(Yb, WpT, b_proj, 8192, 1024, 1024,
                                                nullptr, nullptr, nullptr, out);
}

// Round 9
// 182.732 us; speedup vs baseline: 1.1635x; 1.1635x over previous
//
#include <hip/hip_runtime.h>

// ---------------------------------------------------------------------------
// CausalSelfAttention forward on MI355X (gfx950).
// B=4, T=2048, C=1024, H=16, hs=64.
// Pipeline: [cvt x->bf16, transpose W's] -> QKV GEMM (128x128, 3 blk/CU,
//           M-fastest XCD chunks) -> flash attention (swapped-QK, single
//           q-tile/block, LPT grid) -> proj GEMM.
// Workspace layout (bytes):
//   xb    @ 0         : 8192x1024 bf16           (16,777,216)
//   WaT   @ 16777216  : 3072x1024 bf16           ( 6,291,456)
//   WpT   @ 23068672  : 1024x1024 bf16           ( 2,097,152)
//   Q     @ 25165824  : [64][2048][64] bf16      (pre-scaled by log2e/8)
//   K     @ 41943040  : [64][2048][64] bf16
//   Vt    @ 58720256  : [64][64][2048] bf16      (V transposed per head)
//   Y     @ 75497472  : 8192x1024 bf16
// ---------------------------------------------------------------------------

typedef __bf16 bf16_t;
typedef __bf16 bf16x8 __attribute__((ext_vector_type(8)));
typedef __bf16 bf16x4 __attribute__((ext_vector_type(4)));
typedef float  f32x4  __attribute__((ext_vector_type(4)));

#define MFMA16(a, b, c) __builtin_amdgcn_mfma_f32_16x16x32_bf16((a), (b), (c), 0, 0, 0)

static __device__ __forceinline__ void gld_lds16(const bf16_t* g, void* l) {
  __builtin_amdgcn_global_load_lds(
      (const __attribute__((address_space(1))) void*)(const void*)g,
      (__attribute__((address_space(3))) void*)l, 16, 0, 0);
}

static __device__ __forceinline__ bf16x8 ldv8(const void* p) {
  return *reinterpret_cast<const bf16x8*>(p);
}

static __device__ __forceinline__ float exp2_hw(float x) {
  float r;
  asm("v_exp_f32 %0, %1" : "=v"(r) : "v"(x));
  return r;
}

// ---------------------------------------------------------------- prep ----
__global__ __launch_bounds__(256) void cvt_f32_bf16(const float* __restrict__ in,
                                                    bf16_t* __restrict__ out, int n4) {
  int i = blockIdx.x * 256 + threadIdx.x;
  if (i < n4) {
    float4 v = reinterpret_cast<const float4*>(in)[i];
    bf16x4 o;
    o[0] = (bf16_t)v.x; o[1] = (bf16_t)v.y; o[2] = (bf16_t)v.z; o[3] = (bf16_t)v.w;
    reinterpret_cast<bf16x4*>(out)[i] = o;
  }
}

// in [Kd][Nd] f32  ->  out [Nd][Kd] bf16
__global__ __launch_bounds__(256) void transpose_cvt(const float* __restrict__ in,
                                                     bf16_t* __restrict__ out,
                                                     int Kd, int Nd) {
  __shared__ float tile[32][33];
  int tx = threadIdx.x, ty = threadIdx.y;
  int n0 = blockIdx.x * 32, k0 = blockIdx.y * 32;
#pragma unroll
  for (int i = 0; i < 4; ++i)
    tile[ty + i * 8][tx] = in[(size_t)(k0 + ty + i * 8) * Nd + (n0 + tx)];
  __syncthreads();
#pragma unroll
  for (int i = 0; i < 4; ++i)
    out[(size_t)(n0 + ty + i * 8) * Kd + (k0 + tx)] = (bf16_t)tile[tx][ty + i * 8];
}

// ---------------------------------------------------------------- GEMM ----
// 128x128 tile, BK=64, 4 waves, gld_lds staging w/ source-side XOR swizzle
// (round-7 structure, 3 blocks/CU). XCD mapping: XCD c = lb&7 owns a
// contiguous 8-M-tile slice across all N, ordered M-FASTEST so the N-strip
// working set (8 A-panels = 2MB + 1 B-panel) stays L2-resident and A-panels
// survive across strips. Requires gridDim.y % 8 == 0.
// MODE 0: scatter qkv -> Q (x log2e/8), K, Vt. MODE 1: f32 out.
template <int MODE>
__global__ __launch_bounds__(256) void gemm_bf16(
    const bf16_t* __restrict__ A, const bf16_t* __restrict__ Bt,
    const float* __restrict__ bias, int M, int N, int K,
    bf16_t* __restrict__ Qo, bf16_t* __restrict__ Ko, bf16_t* __restrict__ Vt,
    float* __restrict__ Co) {
  __shared__ alignas(16) char lds[32768];

  const int tid = threadIdx.x;
  const int wave = tid >> 6, lane = tid & 63;
  const int wm = wave >> 1, wn = wave & 1;
  const int l16 = lane & 15, kb = lane >> 4;

  // XCD-chunked, M-fastest tile order
  const int nbx = gridDim.x;
  const int lb = blockIdx.y * nbx + blockIdx.x;
  const int c = lb & 7;                       // XCD (dispatch round-robin)
  const int ii = lb >> 3;                     // position within chunk
  const int rPer = gridDim.y >> 3;            // M-tiles per XCD
  const int tmt = c * rPer + (ii % rPer);     // M-fastest
  const int tnt = ii / rPer;
  const int tm0 = tmt * 128, tn0 = tnt * 128;

  const int srow = wave * 8 + (lane >> 3);
  const int sp = lane & 7;

  f32x4 acc[4][4] = {};

  for (int k0 = 0; k0 < K; k0 += 64) {
    __syncthreads();
#pragma unroll
    for (int inst = 0; inst < 4; ++inst) {
      const int row = inst * 32 + srow;
      const int chunk = (sp ^ (row & 7)) * 8;
      gld_lds16(A + (size_t)(tm0 + row) * K + k0 + chunk,
                &lds[inst * 4096 + wave * 1024]);
      gld_lds16(Bt + (size_t)(tn0 + row) * K + k0 + chunk,
                &lds[16384 + inst * 4096 + wave * 1024]);
    }
    __syncthreads();
#pragma unroll
    for (int kc = 0; kc < 2; ++kc) {
      bf16x8 af[4], bfr[4];
#pragma unroll
      for (int mi = 0; mi < 4; ++mi) {
        const int row = wm * 64 + mi * 16 + l16;
        const int slot = (kc * 4 + kb) ^ (row & 7);
        af[mi] = ldv8(&lds[row * 128 + slot * 16]);
      }
#pragma unroll
      for (int ni = 0; ni < 4; ++ni) {
        const int row = wn * 64 + ni * 16 + l16;
        const int slot = (kc * 4 + kb) ^ (row & 7);
        bfr[ni] = ldv8(&lds[16384 + row * 128 + slot * 16]);
      }
#pragma unroll
      for (int mi = 0; mi < 4; ++mi)
#pragma unroll
        for (int ni = 0; ni < 4; ++ni)
          acc[mi][ni] = MFMA16(af[mi], bfr[ni], acc[mi][ni]);
    }
  }

#pragma unroll
  for (int ni = 0; ni < 4; ++ni) {
    const int n = tn0 + wn * 64 + ni * 16 + l16;
    const float bv = bias[n];
#pragma unroll
    for (int mi = 0; mi < 4; ++mi) {
#pragma unroll
      for (int j = 0; j < 4; ++j) {
        const int m = tm0 + wm * 64 + mi * 16 + kb * 4 + j;
        const float v = acc[mi][ni][j] + bv;
        if constexpr (MODE == 0) {
          const int which = n >> 10, hn = n & 1023;
          const int h = hn >> 6, d = hn & 63;
          const int b = m >> 11, t = m & 2047;
          const size_t bh = (size_t)(b * 16 + h);
          if (which == 0)  // fold 1/sqrt(hs) * log2(e) for base-2 softmax
            Qo[(bh * 2048 + t) * 64 + d] = (bf16_t)(v * 0.18033688011112042f);
          else if (which == 1)
            Ko[(bh * 2048 + t) * 64 + d] = (bf16_t)v;
          else
            Vt[(bh * 64 + d) * 2048 + t] = (bf16_t)v;
        } else {
          Co[(size_t)m * N + n] = v;
        }
      }
    }
  }
}

// ----------------------------------------------------------- attention ----
// Single q-tile per block (64 rows, 4 waves x 16), 2048 blocks, LPT order
// (longest kv-sweep first: qt = 31 - (n>>6)) -> scheduler backfills the tail
// (r7's merged-pair grid was exactly-resident: 20% idle tail). Swapped-QK:
// lane owns one q-row. LDS 40KB (K dbuf 2x8K, V dbuf 2x8K, P 8K) -> 4
// blocks/CU resident + 4 queued. Defer-max base-2 softmax (Q pre-scaled
// log2e/8), diagonal-only masking, per-kb-lane partial l_r reduced in
// epilogue. One vmcnt(0)+barrier per iter. Heads grouped 8-per-XCD.
__global__ __launch_bounds__(256) void attn_fwd(const bf16_t* __restrict__ Qg,
                                                const bf16_t* __restrict__ Kg,
                                                const bf16_t* __restrict__ Vtg,
                                                bf16_t* __restrict__ Yg) {
  __shared__ alignas(16) char lds[40960];  // K 2x8K @0, V 2x8K @16384, P 8K @32768

  const int tid = threadIdx.x;
  const int wave = tid >> 6, lane = tid & 63;
  const int l16 = lane & 15, kb = lane >> 4;
  const int l8 = l16 & 7;
  const float NEG_INF = -__builtin_inff();

  const int n = blockIdx.x;                    // 2048 blocks
  const int bh = (n & 7) * 8 + ((n >> 3) & 7); // 8 heads per XCD
  const int qt = 31 - (n >> 6);                // longest-first (LPT)
  const size_t base = (size_t)bh * (2048 * 64);
  const int b = bh >> 4, h = bh & 15;

  const int srow = tid >> 3;
  const int schunk = (tid & 7) ^ (srow & 7);
  const bf16_t* Ksrc = Kg + base + (size_t)srow * 64 + schunk * 8;
  const bf16_t* Vsrc = Vtg + base + (size_t)srow * 2048 + schunk * 8;

  auto stageK = [&](int buf, int kv0) {
    char* kd = lds + buf * 8192 + wave * 1024;
    const bf16_t* ks = Ksrc + (size_t)kv0 * 64;
    gld_lds16(ks, kd);
    gld_lds16(ks + 2048, kd + 4096);
  };
  auto stageV = [&](int buf, int kv0) {
    char* vd = lds + 16384 + buf * 8192 + wave * 1024;
    const bf16_t* vs = Vsrc + kv0;
    gld_lds16(vs, vd);
    gld_lds16(vs + 65536, vd + 4096);
  };

  const int q0 = qt * 64 + wave * 16;
  const int q = q0 + l16;                      // this lane's q-row
  const int trips = qt + 1;

  const bf16x8 qf0 = ldv8(Qg + base + (size_t)q * 64 + kb * 8);
  const bf16x8 qf1 = ldv8(Qg + base + (size_t)q * 64 + 32 + kb * 8);

  f32x4 o[4] = {};
  float m_r = NEG_INF, l_r = 0.f;

  char* Pw = lds + 32768 + wave * 2048;

  stageK(0, 0);
  stageV(0, 0);
  asm volatile("s_waitcnt vmcnt(0)" ::: "memory");
  __builtin_amdgcn_s_barrier();
  __builtin_amdgcn_sched_barrier(0);

  int cur = 0;
  for (int t = 0; t < trips; ++t) {
    const int kv0 = t * 64;
    const bool more = (t + 1 < trips);
    if (more) {
      stageK(cur ^ 1, kv0 + 64);               // async, drains at iter end
      stageV(cur ^ 1, kv0 + 64);
    }

    const char* Kb = lds + cur * 8192;
    const char* Vb = lds + 16384 + cur * 8192;

    bf16x8 kf[8];
#pragma unroll
    for (int i = 0; i < 4; ++i) {
      const int row = i * 16 + l16;
#pragma unroll
      for (int kc = 0; kc < 2; ++kc)
        kf[i * 2 + kc] = ldv8(Kb + row * 128 + (((kc * 4 + kb) ^ (row & 7)) * 16));
    }

    f32x4 s[4] = {};
    __builtin_amdgcn_s_setprio(1);
#pragma unroll
    for (int i = 0; i < 4; ++i) {
      s[i] = MFMA16(kf[i * 2 + 0], qf0, s[i]);
      s[i] = MFMA16(kf[i * 2 + 1], qf1, s[i]);
    }
    __builtin_amdgcn_s_setprio(0);

    bf16x8 vf[8];
#pragma unroll
    for (int i = 0; i < 4; ++i) {
      const int row = i * 16 + l16;
#pragma unroll
      for (int kc = 0; kc < 2; ++kc)
        vf[i * 2 + kc] = ldv8(Vb + row * 128 + (((kc * 4 + kb) ^ (row & 7)) * 16));
    }

    // --- online softmax, base-2, defer-max, partial l ------------------
    float pm[4];
    if (t == qt) {  // diagonal tile: causal mask (wave-uniform branch)
#pragma unroll
      for (int i = 0; i < 4; ++i) {
        f32x4 sv = s[i];
#pragma unroll
        for (int j = 0; j < 4; ++j)
          if (kv0 + i * 16 + kb * 4 + j > q) sv[j] = NEG_INF;
        s[i] = sv;
        pm[i] = fmaxf(fmaxf(sv[0], sv[1]), fmaxf(sv[2], sv[3]));
      }
    } else {
#pragma unroll
      for (int i = 0; i < 4; ++i)
        pm[i] = fmaxf(fmaxf(s[i][0], s[i][1]), fmaxf(s[i][2], s[i][3]));
    }
    float mx = fmaxf(fmaxf(pm[0], pm[1]), fmaxf(pm[2], pm[3]));
    if (__any(mx > m_r + 8.0f)) {              // rare: full reduce + rescale
      mx = fmaxf(mx, __shfl_xor(mx, 16));
      mx = fmaxf(mx, __shfl_xor(mx, 32));
      const float mn = fmaxf(m_r, mx);
      const float sc = exp2_hw(m_r - mn);
      l_r *= sc;
#pragma unroll
      for (int i = 0; i < 4; ++i) {
        o[i][0] *= sc; o[i][1] *= sc; o[i][2] *= sc; o[i][3] *= sc;
      }
      m_r = mn;
    }
    float ss = 0.f;
    bf16x4 pw[4];
#pragma unroll
    for (int i = 0; i < 4; ++i)
#pragma unroll
      for (int j = 0; j < 4; ++j) {
        const float p = exp2_hw(s[i][j] - m_r);
        ss += p;
        pw[i][j] = (bf16_t)p;
      }
    l_r += ss;                                  // partial; reduced in epilogue

    // P^T roundtrip, wave-private (16B-chunk XOR swizzle; verified r3-r8)
#pragma unroll
    for (int i = 0; i < 4; ++i) {
      const int phys = (i * 2 + (kb >> 1)) ^ l8;
      *reinterpret_cast<bf16x4*>(Pw + l16 * 128 + phys * 16 + (kb & 1) * 8) = pw[i];
    }
    const bf16x8 pb0 = ldv8(Pw + l16 * 128 + ((kb ^ l8) * 16));
    const bf16x8 pb1 = ldv8(Pw + l16 * 128 + (((4 + kb) ^ l8) * 16));

    __builtin_amdgcn_s_setprio(1);
#pragma unroll
    for (int i = 0; i < 4; ++i) {
      o[i] = MFMA16(vf[i * 2 + 0], pb0, o[i]);
      o[i] = MFMA16(vf[i * 2 + 1], pb1, o[i]);
    }
    __builtin_amdgcn_s_setprio(0);

    asm volatile("s_waitcnt vmcnt(0)" ::: "memory");
    __builtin_amdgcn_s_barrier();
    __builtin_amdgcn_sched_barrier(0);
    cur ^= 1;
  }

  float lt = l_r + __shfl_xor(l_r, 16);
  lt += __shfl_xor(lt, 32);
  const float inv = 1.0f / lt;
  bf16_t* yrow = Yg + ((size_t)(b * 2048 + q)) * 1024 + h * 64;
#pragma unroll
  for (int i = 0; i < 4; ++i) {
    bf16x4 yv;
    yv[0] = (bf16_t)(o[i][0] * inv);
    yv[1] = (bf16_t)(o[i][1] * inv);
    yv[2] = (bf16_t)(o[i][2] * inv);
    yv[3] = (bf16_t)(o[i][3] * inv);
    *reinterpret_cast<bf16x4*>(yrow + i * 16 + kb * 4) = yv;
  }
}

// --------------------------------------------------------------- launch ---
extern "C" void kernel_launch(void* const* d_in, const int* in_sizes, int n_in,
                              void* d_out, int out_size, void* d_ws, size_t ws_size,
                              hipStream_t stream) {
  const float* x = (const float*)d_in[0];
  const float* W_attn = (const float*)d_in[1];
  const float* b_attn = (const float*)d_in[2];
  const float* W_proj = (const float*)d_in[3];
  const float* b_proj = (const float*)d_in[4];
  float* out = (float*)d_out;

  char* ws = (char*)d_ws;
  bf16_t* xb  = (bf16_t*)(ws + 0);
  bf16_t* WaT = (bf16_t*)(ws + 16777216);
  bf16_t* WpT = (bf16_t*)(ws + 23068672);
  bf16_t* Qb  = (bf16_t*)(ws + 25165824);
  bf16_t* Kb  = (bf16_t*)(ws + 41943040);
  bf16_t* Vt  = (bf16_t*)(ws + 58720256);
  bf16_t* Yb  = (bf16_t*)(ws + 75497472);

  cvt_f32_bf16<<<8192, 256, 0, stream>>>(x, xb, 8192 * 1024 / 4);
  transpose_cvt<<<dim3(96, 32), dim3(32, 8), 0, stream>>>(W_attn, WaT, 1024, 3072);
  transpose_cvt<<<dim3(32, 32), dim3(32, 8), 0, stream>>>(W_proj, WpT, 1024, 1024);

  // qkv: M=8192, N=3072 -> grid 24x64 = 1536 blocks (6 CU rounds, 3 blk/CU)
  gemm_bf16<0><<<dim3(24, 64), 256, 0, stream>>>(xb, WaT, b_attn, 8192, 3072, 1024,
                                                 Qb, Kb, Vt, nullptr);

  attn_fwd<<<2048, 256, 0, stream>>>(Qb, Kb, Vt, Yb);

  // proj: M=8192, N=1024 -> grid 8x64 = 512 blocks
  gemm_bf16<1><<<dim3(8, 64), 256, 0, stream>>>(Yb, WpT, b_proj, 8192, 1024, 1024,
                                                nullptr, nullptr, nullptr, out);
}